// Round 3
// baseline (358.963 us; speedup 1.0000x reference)
//
#include <hip/hip_runtime.h>

// Pad ragged (sum(seqlen), H) fp32 -> (B=8, S=2048, H=4096) fp32, zero tail.
// Streaming roofline: 128 MiB read + 256 MiB write => ~61 us at 6.3 TB/s.
//
// Structure: one block per output row (B*S = 16384 blocks). Each row is
// 4096 floats = 1024 v4 (16B); 256 threads x 4 v4 each, fully coalesced.
// The valid/tail decision is uniform per row -> block-uniform branch, no
// divergence. Output is written once and never read -> non-temporal stores
// keep it out of L2. Native vector type (ext_vector_type) because the
// nontemporal builtin rejects HIP_vector_type classes.

#define BATCH   8
#define MAXSEQ  2048
#define HV      1024              // 16B-vectors per hidden row (4096/4)

typedef float v4 __attribute__((ext_vector_type(4)));

__global__ __launch_bounds__(256) void pad_kernel(
    const v4* __restrict__ in,
    const int* __restrict__ seqlen,
    v4* __restrict__ out)
{
    __shared__ int slen[BATCH];
    if (threadIdx.x < BATCH) slen[threadIdx.x] = seqlen[threadIdx.x];
    __syncthreads();

    const int blk = blockIdx.x;
    const int b   = blk >> 11;            // row / MAXSEQ
    const int s   = blk & (MAXSEQ - 1);
    const int t   = threadIdx.x;

    v4* orow = out + ((long)blk << 10);   // blk * HV

    if (s < slen[b]) {
        // prefix offset of batch b (uniform, LDS broadcasts — free)
        int off = 0;
#pragma unroll
        for (int i = 0; i < BATCH; ++i) off += (i < b) ? slen[i] : 0;

        const v4* irow = in + ((long)(off + s) << 10);
        v4 v0 = irow[t];
        v4 v1 = irow[t + 256];
        v4 v2 = irow[t + 512];
        v4 v3 = irow[t + 768];
        __builtin_nontemporal_store(v0, orow + t);
        __builtin_nontemporal_store(v1, orow + t + 256);
        __builtin_nontemporal_store(v2, orow + t + 512);
        __builtin_nontemporal_store(v3, orow + t + 768);
    } else {
        const v4 z = {0.f, 0.f, 0.f, 0.f};
        __builtin_nontemporal_store(z, orow + t);
        __builtin_nontemporal_store(z, orow + t + 256);
        __builtin_nontemporal_store(z, orow + t + 512);
        __builtin_nontemporal_store(z, orow + t + 768);
    }
}

extern "C" void kernel_launch(void* const* d_in, const int* in_sizes, int n_in,
                              void* d_out, int out_size, void* d_ws, size_t ws_size,
                              hipStream_t stream)
{
    const v4* in      = (const v4*)d_in[0];
    const int* seqlen = (const int*)d_in[1];
    v4* out           = (v4*)d_out;

    const int blocks = BATCH * MAXSEQ;   // 16384 rows
    pad_kernel<<<blocks, 256, 0, stream>>>(in, seqlen, out);
}